// Round 6
// baseline (125.344 us; speedup 1.0000x reference)
//
#include <hip/hip_runtime.h>
#include <math.h>

// Problem constants (static per reference)
#define NPG     512
#define B_GR    512
#define FDIM    255
#define DEG     32
#define EPG     (NPG * DEG)       // 16384 edges per graph (graph-contiguous)
#define N_NODES (B_GR * NPG)      // 262144
#define E_TOT   (N_NODES * DEG)   // 8388608
#define K_KEEP  256               // ceil(0.5 * NPG)
#define GRP_TOT (N_NODES / 4)     // 65536 4-row groups

// ---------------------------------------------------------------------------
// K1: h[i] = feat[i,:]·W[0:255] + real_i·W[255]
// Pure streaming matvec, no barriers, no staging. Each wave owns a 4-row
// group = 1020 floats = 255 aligned float4. Lane l loads float4 indices
// {l, 64+l, 128+l, 192+l(<255)} directly from global; weights come from a
// 1020-entry replicated LDS table (aligned b128 reads, conflict-free).
// Row boundaries (255/510/765) only affect lane 63 -> compile-time spill fix.
// ---------------------------------------------------------------------------
__global__ __launch_bounds__(256) void k_proj(const float* __restrict__ feat,
                                              const int*   __restrict__ z,
                                              const float* __restrict__ W,
                                              float*       __restrict__ h) {
    __shared__ __align__(16) float Wx[1020];   // Wx[i] = W[i % 255]
    __shared__ float w255s;

    const int tid = threadIdx.x;
    for (int k = tid; k < 1020; k += 256) Wx[k] = W[k % 255];
    if (tid == 0) w255s = W[255];
    __syncthreads();

    const int lane = tid & 63;
    const int wv   = tid >> 6;
    const float4* W4 = (const float4*)Wx;
    const float4* F4 = (const float4*)feat;
    const int4*   Z4 = (const int4*)z;
    float4*       H4 = (float4*)h;
    const float w255 = w255s;
    const bool  l63  = (lane == 63);

    // per-lane weight fragments (loop-invariant)
    const float4 wf0 = W4[lane];
    const float4 wf1 = W4[64 + lane];
    const float4 wf2 = W4[128 + lane];
    const float4 wf3 = l63 ? make_float4(0.f, 0.f, 0.f, 0.f) : W4[192 + lane];

    const int nwaves = gridDim.x * 4;
    for (int grp = blockIdx.x * 4 + wv; grp < GRP_TOT; grp += nwaves) {
        const float4* src = F4 + (size_t)grp * 255;
        const float4 a = src[lane];
        const float4 b = src[64 + lane];
        const float4 c = src[128 + lane];
        const float4 d = l63 ? make_float4(0.f, 0.f, 0.f, 0.f) : src[192 + lane];

        // element i = 256r + 4*lane + j ; row = i/255 ; spill iff lane==63 && j>=3-r
        float acc0 = a.x * wf0.x + a.y * wf0.y + a.z * wf0.z;
        const float p03 = a.w * wf0.w;                    // r0 j3
        float acc1 = b.x * wf1.x + b.y * wf1.y;
        const float p12 = b.z * wf1.z, p13 = b.w * wf1.w; // r1 j2,j3
        float acc2 = c.x * wf2.x;
        const float p21 = c.y * wf2.y, p22 = c.z * wf2.z, p23 = c.w * wf2.w;
        float acc3 = d.x * wf3.x + d.y * wf3.y + d.z * wf3.z + d.w * wf3.w;

        const float q03 = p03;
        const float q1  = p12 + p13;
        const float q2  = p21 + p22 + p23;
        acc0 += l63 ? 0.f : q03;
        acc1 += l63 ? q03 : q1;
        acc2 += l63 ? q1  : q2;
        acc3 += l63 ? q2  : 0.f;

#pragma unroll
        for (int off = 32; off; off >>= 1) {
            acc0 += __shfl_down(acc0, off, 64);
            acc1 += __shfl_down(acc1, off, 64);
            acc2 += __shfl_down(acc2, off, 64);
            acc3 += __shfl_down(acc3, off, 64);
        }
        if (lane == 0) {
            const int4 zz = Z4[grp];
            float4 hv;
            hv.x = acc0 + ((zz.x != 100) ? w255 : 0.f);
            hv.y = acc1 + ((zz.y != 100) ? w255 : 0.f);
            hv.z = acc2 + ((zz.z != 100) ? w255 : 0.f);
            hv.w = acc3 + ((zz.w != 100) ? w255 : 0.f);
            H4[grp] = hv;
        }
    }
}

// ---------------------------------------------------------------------------
// K2: one 1024-thread block per graph (2/CU).
//  B: deg (col cached as ushort in LDS) -> dinv -> v = dinv*h ->
//     agg_raw[c] = v_c + sum v_r (1 LDS read + 1 LDS atomic per edge)
//  C: score = tanh(dinv*agg_raw + b) -> float4 rank-count top-K
//  D: gated gather-mean (8-batched loads) into d_out[g, 0:256]
// ---------------------------------------------------------------------------
__global__ __launch_bounds__(1024) void k_score(const float* __restrict__ feat,
                                                const int*   __restrict__ z,
                                                const int*   __restrict__ ei,
                                                const float* __restrict__ bias,
                                                const float* __restrict__ h,
                                                float*       __restrict__ outp) {
    __shared__ ushort4 cc4[EPG / 4];            // 32 KB local col cache
    __shared__ __align__(16) float score[NPG];
    __shared__ float v_l[NPG];                  // v = dinv*h
    __shared__ float dinv_l[NPG];
    __shared__ float agg[NPG];
    __shared__ float realb[NPG];
    __shared__ int   deg[NPG];
    __shared__ int   rank2[2][NPG];
    __shared__ int   selidx[K_KEEP];
    __shared__ float selsc[K_KEEP];
    __shared__ float red[3][256];
    __shared__ int   cnt;

    const int g     = blockIdx.x;
    const int tid   = threadIdx.x;
    const int nbase = g * NPG;

    const int4* colp4 = (const int4*)(ei + (size_t)E_TOT + (size_t)g * EPG);
    const int4* rowp4 = (const int4*)(ei + (size_t)g * EPG);

    if (tid < NPG) {
        v_l[tid]   = h[nbase + tid];            // raw h for now
        realb[tid] = (z[nbase + tid] != 100) ? 1.f : 0.f;
        deg[tid]   = 1;                         // self-loop
    }
    if (tid == 0) cnt = 0;
    __syncthreads();

    // pass 1: in-degree + col cache
#pragma unroll
    for (int it = 0; it < 4; ++it) {
        const int  idx = it * 1024 + tid;
        const int4 c4  = colp4[idx];
        ushort4 u;
        u.x = (unsigned short)(c4.x - nbase);
        u.y = (unsigned short)(c4.y - nbase);
        u.z = (unsigned short)(c4.z - nbase);
        u.w = (unsigned short)(c4.w - nbase);
        cc4[idx] = u;
        atomicAdd(&deg[u.x], 1);
        atomicAdd(&deg[u.y], 1);
        atomicAdd(&deg[u.z], 1);
        atomicAdd(&deg[u.w], 1);
    }
    __syncthreads();

    if (tid < NPG) {
        const float di = (float)(1.0 / sqrt((double)deg[tid]));  // np-exact rsqrt
        dinv_l[tid] = di;
        const float v = di * v_l[tid];
        v_l[tid] = v;
        agg[tid] = v;                           // self-loop term
    }
    __syncthreads();

    // pass 2: agg_raw[c] += v[r]
#pragma unroll
    for (int it = 0; it < 4; ++it) {
        const int     idx = it * 1024 + tid;
        const int4    r4  = rowp4[idx];
        const ushort4 u   = cc4[idx];
        atomicAdd(&agg[u.x], v_l[r4.x - nbase]);
        atomicAdd(&agg[u.y], v_l[r4.y - nbase]);
        atomicAdd(&agg[u.z], v_l[r4.z - nbase]);
        atomicAdd(&agg[u.w], v_l[r4.w - nbase]);
    }
    __syncthreads();

    // score + top-K selection
    if (tid < NPG)
        score[tid] = tanhf(fmaf(agg[tid], dinv_l[tid], bias[0]));
    __syncthreads();

    {
        const int     node = tid & (NPG - 1);
        const int     half = tid >> 9;
        const float   sc   = score[node];
        const float4* s4p  = (const float4*)&score[half * 256];
        int part = 0;
#pragma unroll 8
        for (int i = 0; i < 64; ++i) {
            const float4 s4 = s4p[i];           // broadcast b128 read
            const int    j  = half * 256 + i * 4;
            part += (s4.x > sc) || (s4.x == sc && (j + 0) < node);
            part += (s4.y > sc) || (s4.y == sc && (j + 1) < node);
            part += (s4.z > sc) || (s4.z == sc && (j + 2) < node);
            part += (s4.w > sc) || (s4.w == sc && (j + 3) < node);
        }
        rank2[half][node] = part;
    }
    __syncthreads();

    if (tid < NPG) {
        const int rank = rank2[0][tid] + rank2[1][tid];
        if (rank < K_KEEP) {                    // jax tie-break: lower idx wins
            const int slot = atomicAdd(&cnt, 1);
            selidx[slot] = tid;
            selsc[slot]  = score[tid];
        }
    }
    __syncthreads();

    // gated gather-mean (8-batched loads)
    {
        const int f = tid & 255;
        const int q = tid >> 8;                 // 4 quarters; s = q + 4k
        float acc = 0.f;
        if (f < FDIM) {
            const float* fb = feat + (size_t)nbase * FDIM + f;
#pragma unroll
            for (int k = 0; k < 64; k += 8) {
                int   is[8]; float ss[8]; float tv[8];
#pragma unroll
                for (int j = 0; j < 8; ++j) {
                    is[j] = selidx[q + 4 * (k + j)];
                    ss[j] = selsc [q + 4 * (k + j)];
                }
#pragma unroll
                for (int j = 0; j < 8; ++j)
                    tv[j] = fb[(size_t)is[j] * FDIM];
#pragma unroll
                for (int j = 0; j < 8; ++j)
                    acc = fmaf(ss[j], tv[j], acc);
            }
        } else {                                // f == 255: real bit
            for (int s = q; s < K_KEEP; s += 4)
                acc = fmaf(selsc[s], realb[selidx[s]], acc);
        }
        if (q) red[q - 1][f] = acc;
        __syncthreads();
        if (q == 0)
            outp[(size_t)g * 256 + f] =
                (acc + red[0][f] + red[1][f] + red[2][f]) * (1.f / K_KEEP);
    }
}

extern "C" void kernel_launch(void* const* d_in, const int* in_sizes, int n_in,
                              void* d_out, int out_size, void* d_ws, size_t ws_size,
                              hipStream_t stream) {
    const float* feat = (const float*)d_in[0];   // out: [N, F] f32
    const int*   z    = (const int*)  d_in[1];   // z:   [N] i32
    const int*   ei   = (const int*)  d_in[2];   // edge_index: [2, E] i32
    // d_in[3] = batch (unused), d_in[6] = edge_attr (unused)
    const float* W    = (const float*)d_in[4];   // [F+1] f32
    const float* bias = (const float*)d_in[5];   // [1] f32
    float* outp = (float*)d_out;                 // [B, F+1] f32
    float* h    = (float*)d_ws;                  // N floats scratch

    k_proj <<<2048, 256,  0, stream>>>(feat, z, W, h);
    k_score<<<B_GR, 1024, 0, stream>>>(feat, z, ei, bias, h, outp);
}